// Round 1
// baseline (2239.754 us; speedup 1.0000x reference)
//
#include <hip/hip_runtime.h>
#include <hip/hip_bf16.h>

#define NN 100000
#define EE 1600000
#define HH 64
#define GG 512

// ---- degree: atomicAdd over dst ----
__global__ void deg_kernel(const int* __restrict__ ei, float* __restrict__ deg, int E_) {
    int e = blockIdx.x * 256 + threadIdx.x;
    if (e < E_) atomicAdd(&deg[ei[E_ + e]], 1.0f);
}

// ---- dinv = 1/sqrt(deg_edges + 1 self-loop), in place ----
__global__ void dinv_kernel(float* __restrict__ deg, int n) {
    int i = blockIdx.x * 256 + threadIdx.x;
    if (i < n) deg[i] = 1.0f / sqrtf(deg[i] + 1.0f);
}

// ---- column stats: stats[0:64]=sum, stats[64:128]=sumsq ----
__global__ void colstats(const float* __restrict__ A, int nrows, float* __restrict__ stats) {
    __shared__ float ssum[4][64];
    __shared__ float ssq[4][64];
    int tid = threadIdx.x;
    int col = tid & 63, rg = tid >> 6;
    float s = 0.f, q = 0.f;
    for (int r = blockIdx.x * 4 + rg; r < nrows; r += gridDim.x * 4) {
        float v = A[r * 64 + col];
        s += v;
        q = fmaf(v, v, q);
    }
    ssum[rg][col] = s; ssq[rg][col] = q;
    __syncthreads();
    if (tid < 64) {
        float ts = ssum[0][tid] + ssum[1][tid] + ssum[2][tid] + ssum[3][tid];
        float tq = ssq[0][tid] + ssq[1][tid] + ssq[2][tid] + ssq[3][tid];
        atomicAdd(&stats[tid], ts);
        atomicAdd(&stats[64 + tid], tq);
    }
}

// ---- fold BN into weights: Wp[k][j] = rstd*g*W ; bp[j] = basebias + sum_k (beta - mu*rstd*g)*W ----
__global__ void prep(const float* __restrict__ stats, float count,
                     const float* __restrict__ g, const float* __restrict__ b,
                     const float* __restrict__ W, const float* __restrict__ basebias,
                     float* __restrict__ Wp, float* __restrict__ bp) {
    int j = threadIdx.x;  // 64 threads
    float acc = basebias ? basebias[j] : 0.f;
    for (int k = 0; k < 64; k++) {
        float mu  = stats[k] / count;
        float var = fmaxf(stats[64 + k] / count - mu * mu, 0.f);
        float rstd = rsqrtf(var + 1e-5f);
        float a = rstd * g[k];
        float w = W[k * 64 + j];
        Wp[k * 64 + j] = a * w;
        acc = fmaf(b[k] - mu * a, w, acc);
    }
    bp[j] = acc;
}

// ---- C[r][j] = (relu?)(sum_k A[r][k]*Wp[k][j] + bp[j]) ; 64-row tiles ----
__global__ __launch_bounds__(256) void gemm64(const float* __restrict__ A,
                                              const float* __restrict__ Wp,
                                              const float* __restrict__ bp,
                                              float* __restrict__ C, int nrows, int dorelu) {
    __shared__ float Ws[64 * 64];
    __shared__ float As[64 * 64];
    int tid = threadIdx.x;
    int row0 = blockIdx.x * 64;
    for (int i = tid; i < 4096; i += 256) {
        Ws[i] = Wp[i];
        int r = row0 + (i >> 6);
        As[i] = (r < nrows) ? A[row0 * 64 + i] : 0.f;
    }
    __syncthreads();
    int col = tid & 63;
    int rg = tid >> 6;  // 0..3
    float bcol = bp[col];
    for (int rr = rg; rr < 64; rr += 4) {
        int r = row0 + rr;
        if (r >= nrows) break;
        float acc = bcol;
#pragma unroll
        for (int k = 0; k < 64; k++) acc = fmaf(As[rr * 64 + k], Ws[k * 64 + col], acc);
        C[r * 64 + col] = dorelu ? fmaxf(acc, 0.f) : acc;
    }
}

// ---- agg init with self-loop contribution: agg = dinv^2 * m ----
__global__ void init_agg(const float* __restrict__ dinv, const float* __restrict__ m,
                         float* __restrict__ agg, int total) {
    int idx = blockIdx.x * 256 + threadIdx.x;
    if (idx < total) {
        float di = dinv[idx >> 6];
        agg[idx] = di * di * m[idx];
    }
}

// ---- edge scatter: agg[dst] += dinv[s]*dinv[d] * m[src] ----
__global__ void scatter(const int* __restrict__ ei, const float* __restrict__ dinv,
                        const float* __restrict__ m, float* __restrict__ agg, int E_) {
    int idx = blockIdx.x * 256 + threadIdx.x;
    if (idx < E_ * 64) {
        int e = idx >> 6, j = idx & 63;
        int s = ei[e], d = ei[E_ + e];
        float nrm = dinv[s] * dinv[d];
        atomicAdd(&agg[d * 64 + j], nrm * m[s * 64 + j]);
    }
}

// ---- residual update: h += relu(agg + conv_b) ----
__global__ void update(float* __restrict__ h, const float* __restrict__ agg,
                       const float* __restrict__ cb, int total) {
    int idx = blockIdx.x * 256 + threadIdx.x;
    if (idx < total) h[idx] += fmaxf(agg[idx] + cb[idx & 63], 0.f);
}

// ---- global add pool ----
__global__ void pool(const int* __restrict__ batch, const float* __restrict__ h,
                     float* __restrict__ pooled, int total) {
    int idx = blockIdx.x * 256 + threadIdx.x;
    if (idx < total) {
        int n = idx >> 6, j = idx & 63;
        atomicAdd(&pooled[batch[n] * 64 + j], h[idx]);
    }
}

// ---- final BN apply ----
__global__ void bn_apply(const float* __restrict__ A, const float* __restrict__ stats, float count,
                         const float* __restrict__ g, const float* __restrict__ b,
                         float* __restrict__ out, int total) {
    int idx = blockIdx.x * 256 + threadIdx.x;
    if (idx < total) {
        int j = idx & 63;
        float mu  = stats[j] / count;
        float var = fmaxf(stats[64 + j] / count - mu * mu, 0.f);
        float rstd = rsqrtf(var + 1e-5f);
        out[idx] = (A[idx] - mu) * rstd * g[j] + b[j];
    }
}

extern "C" void kernel_launch(void* const* d_in, const int* in_sizes, int n_in,
                              void* d_out, int out_size, void* d_ws, size_t ws_size,
                              hipStream_t stream) {
    const float* x     = (const float*)d_in[0];
    const int*   ei    = (const int*)d_in[1];
    const int*   batch = (const int*)d_in[2];
    const float* bnfg  = (const float*)d_in[3];
    const float* bnfb  = (const float*)d_in[4];
    const float* linW  = (const float*)d_in[5];
    const float* linb  = (const float*)d_in[6];
    const float* bncg  = (const float*)d_in[7];
    const float* bncb  = (const float*)d_in[8];
    const float* convW = (const float*)d_in[9];
    const float* convb = (const float*)d_in[10];
    const float* bnfcg = (const float*)d_in[11];
    const float* bnfcb = (const float*)d_in[12];
    const float* fcW   = (const float*)d_in[13];
    const float* fcb   = (const float*)d_in[14];
    const float* bnhg  = (const float*)d_in[15];
    const float* bnhb  = (const float*)d_in[16];

    const int N64 = NN * 64;          // 6,400,000
    float* ws   = (float*)d_ws;
    float* deg  = ws;                 // N floats (becomes dinv)
    float* h    = ws + 100352;        // N*64
    float* m    = h + N64;            // N*64
    float* agg  = m + N64;            // N*64
    float* stats= agg + N64;          // 128
    float* Wp   = stats + 128;        // 4096
    float* bp   = Wp + 4096;          // 64
    float* pa   = bp + 64;            // G*64
    float* pb   = pa + GG * 64;       // G*64

    // --- degree / dinv ---
    hipMemsetAsync(deg, 0, NN * sizeof(float), stream);
    deg_kernel<<<(EE + 255) / 256, 256, 0, stream>>>(ei, deg, EE);
    dinv_kernel<<<(NN + 255) / 256, 256, 0, stream>>>(deg, NN);

    // --- stem: h = relu(BN(x)@linW + linb) ---
    hipMemsetAsync(stats, 0, 512, stream);
    colstats<<<256, 256, 0, stream>>>(x, NN, stats);
    prep<<<1, 64, 0, stream>>>(stats, (float)NN, bnfg, bnfb, linW, linb, Wp, bp);
    gemm64<<<(NN + 63) / 64, 256, 0, stream>>>(x, Wp, bp, h, NN, 1);

    // --- conv layers ---
    for (int l = 0; l < 4; l++) {
        hipMemsetAsync(stats, 0, 512, stream);
        colstats<<<256, 256, 0, stream>>>(h, NN, stats);
        prep<<<1, 64, 0, stream>>>(stats, (float)NN, bncg + 64 * l, bncb + 64 * l,
                                   convW + 4096 * l, nullptr, Wp, bp);
        gemm64<<<(NN + 63) / 64, 256, 0, stream>>>(h, Wp, bp, m, NN, 0);
        init_agg<<<(N64 + 255) / 256, 256, 0, stream>>>(deg, m, agg, N64);
        scatter<<<(EE * 64) / 256, 256, 0, stream>>>(ei, deg, m, agg, EE);
        update<<<(N64 + 255) / 256, 256, 0, stream>>>(h, agg, convb + 64 * l, N64);
    }

    // --- global add pool ---
    hipMemsetAsync(pa, 0, GG * 64 * sizeof(float), stream);
    pool<<<(N64 + 255) / 256, 256, 0, stream>>>(batch, h, pa, N64);

    // --- fc head ---
    float* pin = pa; float* pout = pb;
    for (int i = 0; i < 2; i++) {
        hipMemsetAsync(stats, 0, 512, stream);
        colstats<<<8, 256, 0, stream>>>(pin, GG, stats);
        prep<<<1, 64, 0, stream>>>(stats, (float)GG, bnfcg + 64 * i, bnfcb + 64 * i,
                                   fcW + 4096 * i, fcb + 64 * i, Wp, bp);
        gemm64<<<(GG + 63) / 64, 256, 0, stream>>>(pin, Wp, bp, pout, GG, 1);
        float* t = pin; pin = pout; pout = t;
    }

    // --- final BN -> d_out ---
    hipMemsetAsync(stats, 0, 512, stream);
    colstats<<<8, 256, 0, stream>>>(pin, GG, stats);
    bn_apply<<<(GG * 64 + 255) / 256, 256, 0, stream>>>(pin, stats, (float)GG, bnhg, bnhb,
                                                        (float*)d_out, GG * 64);
}

// Round 2
// 1290.296 us; speedup vs baseline: 1.7358x; 1.7358x over previous
//
#include <hip/hip_runtime.h>
#include <hip/hip_bf16.h>

#define NN 100000
#define EE 1600000
#define GG 512
#define NB ((NN + 255) / 256)   // 391 blocks for node-sized scans

// ---- in-degree histogram (int) ----
__global__ void deg_kernel(const int* __restrict__ ei, int* __restrict__ cnt, int E_) {
    int e = blockIdx.x * 256 + threadIdx.x;
    if (e < E_) atomicAdd(&cnt[ei[E_ + e]], 1);
}

// ---- dinv = 1/sqrt(cnt + 1 self-loop) ----
__global__ void dinv_kernel(const int* __restrict__ cnt, float* __restrict__ dinv, int n) {
    int i = blockIdx.x * 256 + threadIdx.x;
    if (i < n) dinv[i] = rsqrtf((float)cnt[i] + 1.0f);
}

// ---- block sums for scan ----
__global__ void blocksum(const int* __restrict__ cnt, int* __restrict__ bsum) {
    __shared__ int sh[256];
    int i = blockIdx.x * 256 + threadIdx.x;
    sh[threadIdx.x] = (i < NN) ? cnt[i] : 0;
    __syncthreads();
    for (int o = 128; o > 0; o >>= 1) {
        if (threadIdx.x < o) sh[threadIdx.x] += sh[threadIdx.x + o];
        __syncthreads();
    }
    if (threadIdx.x == 0) bsum[blockIdx.x] = sh[0];
}

// ---- exclusive scan of block sums (1 block, 512 threads, nb<=512) ----
__global__ void scan_bsum(int* __restrict__ bsum, int nb) {
    __shared__ int sh[512];
    int t = threadIdx.x;
    int v = (t < nb) ? bsum[t] : 0;
    int orig = v;
    sh[t] = v;
    __syncthreads();
    for (int o = 1; o < 512; o <<= 1) {
        int add = (t >= o) ? sh[t - o] : 0;
        __syncthreads();
        sh[t] += add;
        __syncthreads();
    }
    if (t < nb) bsum[t] = sh[t] - orig;   // exclusive
}

// ---- final scan: row_ptr + cursor ----
__global__ void scan_final(const int* __restrict__ cnt, const int* __restrict__ boff,
                           int* __restrict__ row_ptr, int* __restrict__ cursor) {
    __shared__ int sh[256];
    int i = blockIdx.x * 256 + threadIdx.x;
    int v = (i < NN) ? cnt[i] : 0;
    int orig = v;
    sh[threadIdx.x] = v;
    __syncthreads();
    for (int o = 1; o < 256; o <<= 1) {
        int add = (threadIdx.x >= o) ? sh[threadIdx.x - o] : 0;
        __syncthreads();
        sh[threadIdx.x] += add;
        __syncthreads();
    }
    if (i < NN) {
        int ex = boff[blockIdx.x] + sh[threadIdx.x] - orig;
        row_ptr[i] = ex;
        cursor[i] = ex;
    }
    if (i == 0) row_ptr[NN] = EE;
}

// ---- fill CSR (src + precomputed norm), bucketed by dst ----
__global__ void fill_csr(const int* __restrict__ ei, const float* __restrict__ dinv,
                         int* __restrict__ cursor, int* __restrict__ csr_src,
                         float* __restrict__ csr_norm, int E_) {
    int e = blockIdx.x * 256 + threadIdx.x;
    if (e < E_) {
        int s = ei[e], d = ei[E_ + e];
        int pos = atomicAdd(&cursor[d], 1);
        csr_src[pos] = s;
        csr_norm[pos] = dinv[s] * dinv[d];
    }
}

// ---- column stats: stats[0:64]=sum, stats[64:128]=sumsq ----
__global__ void colstats(const float* __restrict__ A, int nrows, float* __restrict__ stats) {
    __shared__ float ssum[4][64];
    __shared__ float ssq[4][64];
    int tid = threadIdx.x;
    int col = tid & 63, rg = tid >> 6;
    float s = 0.f, q = 0.f;
    for (int r = blockIdx.x * 4 + rg; r < nrows; r += gridDim.x * 4) {
        float v = A[r * 64 + col];
        s += v;
        q = fmaf(v, v, q);
    }
    ssum[rg][col] = s; ssq[rg][col] = q;
    __syncthreads();
    if (tid < 64) {
        float ts = ssum[0][tid] + ssum[1][tid] + ssum[2][tid] + ssum[3][tid];
        float tq = ssq[0][tid] + ssq[1][tid] + ssq[2][tid] + ssq[3][tid];
        atomicAdd(&stats[tid], ts);
        atomicAdd(&stats[64 + tid], tq);
    }
}

// ---- fold BN into weights ----
__global__ void prep(const float* __restrict__ stats, float count,
                     const float* __restrict__ g, const float* __restrict__ b,
                     const float* __restrict__ W, const float* __restrict__ basebias,
                     float* __restrict__ Wp, float* __restrict__ bp) {
    int j = threadIdx.x;  // 64 threads
    float acc = basebias ? basebias[j] : 0.f;
    for (int k = 0; k < 64; k++) {
        float mu  = stats[k] / count;
        float var = fmaxf(stats[64 + k] / count - mu * mu, 0.f);
        float rstd = rsqrtf(var + 1e-5f);
        float a = rstd * g[k];
        float w = W[k * 64 + j];
        Wp[k * 64 + j] = a * w;
        acc = fmaf(b[k] - mu * a, w, acc);
    }
    bp[j] = acc;
}

// ---- C = (relu?)(A@Wp + bp), optional fused column stats of C ----
__global__ __launch_bounds__(256) void gemm64(const float* __restrict__ A,
                                              const float* __restrict__ Wp,
                                              const float* __restrict__ bp,
                                              float* __restrict__ C, int nrows, int dorelu,
                                              float* __restrict__ stats) {
    __shared__ float Ws[64 * 64];
    __shared__ float As[64 * 64];
    __shared__ float ssh[256];
    __shared__ float qsh[256];
    int tid = threadIdx.x;
    int row0 = blockIdx.x * 64;
    for (int i = tid; i < 4096; i += 256) {
        Ws[i] = Wp[i];
        int r = row0 + (i >> 6);
        As[i] = (r < nrows) ? A[row0 * 64 + i] : 0.f;
    }
    __syncthreads();
    int col = tid & 63;
    int rg = tid >> 6;  // 0..3
    float bcol = bp[col];
    float s = 0.f, q = 0.f;
    for (int rr = rg; rr < 64; rr += 4) {
        int r = row0 + rr;
        if (r >= nrows) break;
        float acc = bcol;
#pragma unroll
        for (int k = 0; k < 64; k++) acc = fmaf(As[rr * 64 + k], Ws[k * 64 + col], acc);
        float v = dorelu ? fmaxf(acc, 0.f) : acc;
        C[r * 64 + col] = v;
        s += v;
        q = fmaf(v, v, q);
    }
    if (stats) {
        ssh[tid] = s; qsh[tid] = q;
        __syncthreads();
        if (tid < 64) {
            float ts = ssh[tid] + ssh[64 + tid] + ssh[128 + tid] + ssh[192 + tid];
            float tq = qsh[tid] + qsh[64 + tid] + qsh[128 + tid] + qsh[192 + tid];
            atomicAdd(&stats[tid], ts);
            atomicAdd(&stats[64 + tid], tq);
        }
    }
}

// ---- fused CSR gather: hn = h + relu(dinv^2*m[i] + sum_e norm*m[src] + cb)
//      optional: write h, accumulate next-layer BN stats, atomic pool ----
__global__ __launch_bounds__(256) void gather(const int* __restrict__ row_ptr,
                                              const int* __restrict__ csr_src,
                                              const float* __restrict__ csr_norm,
                                              const float* __restrict__ dinv,
                                              const float* __restrict__ m,
                                              float* __restrict__ h,
                                              const float* __restrict__ cb,
                                              float* __restrict__ stats,
                                              float* __restrict__ pooled,
                                              const int* __restrict__ batch,
                                              int writeH) {
    int tid = threadIdx.x;
    int ng = tid >> 4;        // 16 nodes per block
    int cl = tid & 15;        // 16 col-groups of 4
    const float4* cb4 = (const float4*)cb;
    float4 cbv = cb4[cl];
    float sx = 0.f, sy = 0.f, sz = 0.f, sw = 0.f;
    float qx = 0.f, qy = 0.f, qz = 0.f, qw = 0.f;
    for (int i = blockIdx.x * 16 + ng; i < NN; i += gridDim.x * 16) {
        float di = dinv[i];
        float4 mi = ((const float4*)(m + i * 64))[cl];
        float d2 = di * di;
        float ax = d2 * mi.x, ay = d2 * mi.y, az = d2 * mi.z, aw = d2 * mi.w;
        int e0 = row_ptr[i], e1 = row_ptr[i + 1];
        for (int e = e0; e < e1; e++) {
            int s = csr_src[e];
            float w = csr_norm[e];
            float4 ms = ((const float4*)(m + s * 64))[cl];
            ax = fmaf(w, ms.x, ax);
            ay = fmaf(w, ms.y, ay);
            az = fmaf(w, ms.z, az);
            aw = fmaf(w, ms.w, aw);
        }
        float4 hb = ((const float4*)(h + i * 64))[cl];
        float nx = hb.x + fmaxf(ax + cbv.x, 0.f);
        float ny = hb.y + fmaxf(ay + cbv.y, 0.f);
        float nz = hb.z + fmaxf(az + cbv.z, 0.f);
        float nw = hb.w + fmaxf(aw + cbv.w, 0.f);
        if (writeH) {
            float4 o; o.x = nx; o.y = ny; o.z = nz; o.w = nw;
            ((float4*)(h + i * 64))[cl] = o;
        }
        if (stats) {
            sx += nx; sy += ny; sz += nz; sw += nw;
            qx = fmaf(nx, nx, qx); qy = fmaf(ny, ny, qy);
            qz = fmaf(nz, nz, qz); qw = fmaf(nw, nw, qw);
        }
        if (pooled) {
            int g = batch[i];
            float* p = pooled + g * 64 + cl * 4;
            atomicAdd(p + 0, nx);
            atomicAdd(p + 1, ny);
            atomicAdd(p + 2, nz);
            atomicAdd(p + 3, nw);
        }
    }
    if (stats) {
        __shared__ float rs[256 * 4];
        __shared__ float rq[256 * 4];
        rs[tid * 4 + 0] = sx; rs[tid * 4 + 1] = sy; rs[tid * 4 + 2] = sz; rs[tid * 4 + 3] = sw;
        rq[tid * 4 + 0] = qx; rq[tid * 4 + 1] = qy; rq[tid * 4 + 2] = qz; rq[tid * 4 + 3] = qw;
        __syncthreads();
        if (tid < 64) {  // tid = cl*4+k  -> column cl*4+k
            int cl2 = tid >> 2, k = tid & 3;
            float a = 0.f, b = 0.f;
            for (int g = 0; g < 16; g++) {
                a += rs[(g * 16 + cl2) * 4 + k];
                b += rq[(g * 16 + cl2) * 4 + k];
            }
            atomicAdd(&stats[tid], a);
            atomicAdd(&stats[64 + tid], b);
        }
    }
}

// ---- final BN apply ----
__global__ void bn_apply(const float* __restrict__ A, const float* __restrict__ stats, float count,
                         const float* __restrict__ g, const float* __restrict__ b,
                         float* __restrict__ out, int total) {
    int idx = blockIdx.x * 256 + threadIdx.x;
    if (idx < total) {
        int j = idx & 63;
        float mu  = stats[j] / count;
        float var = fmaxf(stats[64 + j] / count - mu * mu, 0.f);
        float rstd = rsqrtf(var + 1e-5f);
        out[idx] = (A[idx] - mu) * rstd * g[j] + b[j];
    }
}

extern "C" void kernel_launch(void* const* d_in, const int* in_sizes, int n_in,
                              void* d_out, int out_size, void* d_ws, size_t ws_size,
                              hipStream_t stream) {
    const float* x     = (const float*)d_in[0];
    const int*   ei    = (const int*)d_in[1];
    const int*   batch = (const int*)d_in[2];
    const float* bnfg  = (const float*)d_in[3];
    const float* bnfb  = (const float*)d_in[4];
    const float* linW  = (const float*)d_in[5];
    const float* linb  = (const float*)d_in[6];
    const float* bncg  = (const float*)d_in[7];
    const float* bncb  = (const float*)d_in[8];
    const float* convW = (const float*)d_in[9];
    const float* convb = (const float*)d_in[10];
    const float* bnfcg = (const float*)d_in[11];
    const float* bnfcb = (const float*)d_in[12];
    const float* fcW   = (const float*)d_in[13];
    const float* fcb   = (const float*)d_in[14];
    const float* bnhg  = (const float*)d_in[15];
    const float* bnhb  = (const float*)d_in[16];

    const int N64 = NN * 64;
    float* ws = (float*)d_ws;
    size_t o = 0;
    int*   cnt      = (int*)(ws + o);   o += 100352;
    float* dinv     = ws + o;           o += 100352;
    int*   row_ptr  = (int*)(ws + o);   o += 100352;
    int*   cursor   = (int*)(ws + o);   o += 100352;
    int*   bsum     = (int*)(ws + o);   o += 512;
    int*   csr_src  = (int*)(ws + o);   o += EE;
    float* csr_norm = ws + o;           o += EE;
    float* h        = ws + o;           o += N64;
    float* m        = ws + o;           o += N64;
    float* statsA   = ws + o;           o += 128;
    float* statsB   = ws + o;           o += 128;
    float* Wp       = ws + o;           o += 4096;
    float* bp       = ws + o;           o += 64;
    float* pa       = ws + o;           o += GG * 64;
    float* pb       = ws + o;           o += GG * 64;

    // --- CSR build ---
    hipMemsetAsync(cnt, 0, NN * sizeof(int), stream);
    deg_kernel<<<(EE + 255) / 256, 256, 0, stream>>>(ei, cnt, EE);
    dinv_kernel<<<NB, 256, 0, stream>>>(cnt, dinv, NN);
    blocksum<<<NB, 256, 0, stream>>>(cnt, bsum);
    scan_bsum<<<1, 512, 0, stream>>>(bsum, NB);
    scan_final<<<NB, 256, 0, stream>>>(cnt, bsum, row_ptr, cursor);
    fill_csr<<<(EE + 255) / 256, 256, 0, stream>>>(ei, dinv, cursor, csr_src, csr_norm, EE);

    // --- stem: h = relu(BN(x)@linW + linb), fused stats(h) -> statsB ---
    hipMemsetAsync(statsA, 0, 512, stream);
    colstats<<<256, 256, 0, stream>>>(x, NN, statsA);
    prep<<<1, 64, 0, stream>>>(statsA, (float)NN, bnfg, bnfb, linW, linb, Wp, bp);
    hipMemsetAsync(statsB, 0, 512, stream);
    gemm64<<<(NN + 63) / 64, 256, 0, stream>>>(x, Wp, bp, h, NN, 1, statsB);

    // --- conv layers ---
    hipMemsetAsync(pa, 0, GG * 64 * sizeof(float), stream);
    float* cur = statsB; float* nxt = statsA;
    for (int l = 0; l < 4; l++) {
        prep<<<1, 64, 0, stream>>>(cur, (float)NN, bncg + 64 * l, bncb + 64 * l,
                                   convW + 4096 * l, nullptr, Wp, bp);
        gemm64<<<(NN + 63) / 64, 256, 0, stream>>>(h, Wp, bp, m, NN, 0, nullptr);
        if (l < 3) {
            hipMemsetAsync(nxt, 0, 512, stream);
            gather<<<1024, 256, 0, stream>>>(row_ptr, csr_src, csr_norm, dinv, m, h,
                                             convb + 64 * l, nxt, nullptr, batch, 1);
        } else {
            gather<<<1024, 256, 0, stream>>>(row_ptr, csr_src, csr_norm, dinv, m, h,
                                             convb + 64 * l, nullptr, pa, batch, 0);
        }
        float* t = cur; cur = nxt; nxt = t;
    }

    // --- fc head ---
    float* pin = pa; float* pout = pb;
    for (int i = 0; i < 2; i++) {
        hipMemsetAsync(statsA, 0, 512, stream);
        colstats<<<8, 256, 0, stream>>>(pin, GG, statsA);
        prep<<<1, 64, 0, stream>>>(statsA, (float)GG, bnfcg + 64 * i, bnfcb + 64 * i,
                                   fcW + 4096 * i, fcb + 64 * i, Wp, bp);
        gemm64<<<(GG + 63) / 64, 256, 0, stream>>>(pin, Wp, bp, pout, GG, 1, nullptr);
        float* t = pin; pin = pout; pout = t;
    }

    // --- final BN -> d_out ---
    hipMemsetAsync(statsA, 0, 512, stream);
    colstats<<<8, 256, 0, stream>>>(pin, GG, statsA);
    bn_apply<<<(GG * 64 + 255) / 256, 256, 0, stream>>>(pin, statsA, (float)GG, bnhg, bnhb,
                                                        (float*)d_out, GG * 64);
}